// Round 15
// baseline (142.908 us; speedup 1.0000x reference)
//
#include <hip/hip_runtime.h>

// ---------------------------------------------------------------------------
// MultiHeadAttention forward, MI355X (gfx950).
// fp32->bf16 convert; Q/K/V projections (bf16 MFMA GEMM, BK=64 swizzled,
// Q scaled by 0.125*log2e); flash attention v4b (8 waves x 16q, swapped-QK^T,
// defer-max, cvt_pk P-pack, l via ones-MFMA, double-buffered K/V
// counted-vmcnt pipeline); output projection.
// ---------------------------------------------------------------------------

#define D_MODEL 1024
#define NHEADS  16
#define DKH     64
#define SEQ     2048
#define BATCH   2
#define MTOT    (BATCH * SEQ)            // 4096 rows
#define XE      ((long)MTOT * D_MODEL)   // 4194304 elems
#define WE      ((long)D_MODEL * D_MODEL)
#define QSCALE  0.18033688011112042f     // 0.125 * log2(e): softmax in exp2 domain

typedef __attribute__((ext_vector_type(8))) short short8v;   // 8 x bf16 (4 VGPR)
typedef __attribute__((ext_vector_type(4))) short short4v;   // 4 x bf16
typedef __attribute__((ext_vector_type(4))) float f32x4;     // MFMA C/D frag

typedef __attribute__((address_space(1))) void as1_void;
typedef __attribute__((address_space(3))) void as3_void;

__device__ __forceinline__ void gload16(const void* g, void* l) {
    __builtin_amdgcn_global_load_lds((const as1_void*)g, (as3_void*)l, 16, 0, 0);
}

__device__ __forceinline__ unsigned short f2bf(float x) {
    unsigned int u = __float_as_uint(x);
    u += 0x7FFFu + ((u >> 16) & 1u);     // RNE
    return (unsigned short)(u >> 16);
}

// native v_exp_f32: computes 2^x (avoid __exp2f: glibc name collision)
__device__ __forceinline__ float fexp2(float x) {
    return __builtin_amdgcn_exp2f(x);
}

// hardware packed f32x2 -> bf16x2 (one VALU op for two converts)
__device__ __forceinline__ unsigned int cvt_pk_bf16(float lo, float hi) {
    unsigned int r;
    asm("v_cvt_pk_bf16_f32 %0, %1, %2" : "=v"(r) : "v"(lo), "v"(hi));
    return r;
}

// XOR swizzle for [rows][64 bf16] LDS tiles (128B rows).
__device__ __forceinline__ int swz_u(int row, int col) {
    int byte = (col << 1) ^ ((row & 7) << 4);
    return (row << 6) + (byte >> 1);
}

// Vt swizzle: slot bits from (d&6)|((d>>3)&1): write pairs and reads stay 2-way.
__device__ __forceinline__ int swz_v(int d, int kv) {
    int slot = (d & 6) | ((d >> 3) & 1);
    int byte = (kv << 1) ^ (slot << 4);
    return (d << 6) + (byte >> 1);
}

// ---------------------------------------------------------------------------
// fp32 -> bf16 convert, 7 arrays in one launch (blockIdx.y selects array)
// ---------------------------------------------------------------------------
struct ConvArgs {
    const float*    src[7];
    unsigned short* dst[7];
    int             n4[7];
};

__global__ __launch_bounds__(256) void convert_kernel(ConvArgs a) {
    int z = blockIdx.y;
    const float4*   s = (const float4*)a.src[z];
    unsigned short* d = a.dst[z];
    int n = a.n4[z];
    for (int i = blockIdx.x * blockDim.x + threadIdx.x; i < n;
         i += gridDim.x * blockDim.x) {
        float4 v = s[i];
        ushort4 o;
        o.x = f2bf(v.x); o.y = f2bf(v.y); o.z = f2bf(v.z); o.w = f2bf(v.w);
        *(ushort4*)(d + 4L * i) = o;
    }
}

// ---------------------------------------------------------------------------
// GEMM: C[M,N] = A[M,K] * Bm[N,K]^T  (both K-major), + bias, * scale.
// 128x128 tile, BK=64 (halved barrier count vs BK=32), 4 waves (2x2),
// 16x16x32 bf16 MFMA, global_load_lds with XOR-swizzled source (rule #21:
// linear LDS dest + pre-swizzled global col) so the 128B-row reads are
// conflict-free.
// ---------------------------------------------------------------------------
__device__ __forceinline__ void stv(float* p, float v)          { *p = v; }
__device__ __forceinline__ void stv(unsigned short* p, float v) { *p = f2bf(v); }

template <typename OutT>
__device__ __forceinline__ void gemm_core(const unsigned short* __restrict__ A,
                                          const unsigned short* __restrict__ Bm,
                                          const float* __restrict__ bias,
                                          OutT* __restrict__ C,
                                          int K, int N, float scale) {
    __shared__ unsigned short As[128 * 64];   // 16 KB
    __shared__ unsigned short Bs[128 * 64];   // 16 KB

    const int t    = threadIdx.x;
    const int lane = t & 63;
    const int w    = t >> 6;
    const int wm   = w >> 1, wn = w & 1;
    const int l15  = lane & 15, g = lane >> 4;
    const long m0  = (long)blockIdx.y * 128;
    const long n0  = (long)blockIdx.x * 128;

    f32x4 acc[4][4] = {};

    // staging: 1024 16B-chunks per matrix, 4 per thread.
    // chunk idx: row = idx>>3, slot = idx&7; global col pre-swizzled by row&7
    // so the LDS tile is XOR-swizzled with a linear gload_lds destination.
    int srow[4], scol[4];
#pragma unroll
    for (int c = 0; c < 4; ++c) {
        int idx = t + c * 256;
        srow[c] = idx >> 3;
        scol[c] = ((idx & 7) ^ (srow[c] & 7)) * 8;
    }

    for (int k0 = 0; k0 < K; k0 += 64) {
#pragma unroll
        for (int c = 0; c < 4; ++c) {
            int idx = t + c * 256;
            gload16(A  + (m0 + srow[c]) * K + k0 + scol[c], &As[idx * 8]);
            gload16(Bm + (n0 + srow[c]) * K + k0 + scol[c], &Bs[idx * 8]);
        }
        __syncthreads();   // drains vmcnt -> LDS valid

#pragma unroll
        for (int kk = 0; kk < 2; ++kk) {
            short8v af[4], bf_[4];
#pragma unroll
            for (int mf = 0; mf < 4; ++mf) {
                int r = wm * 64 + mf * 16 + l15;
                af[mf] = *(const short8v*)&As[r * 64 + (((kk * 4 + g) ^ (r & 7)) * 8)];
            }
#pragma unroll
            for (int nf = 0; nf < 4; ++nf) {
                int r = wn * 64 + nf * 16 + l15;
                bf_[nf] = *(const short8v*)&Bs[r * 64 + (((kk * 4 + g) ^ (r & 7)) * 8)];
            }
#pragma unroll
            for (int mf = 0; mf < 4; ++mf)
#pragma unroll
                for (int nf = 0; nf < 4; ++nf)
                    acc[mf][nf] = __builtin_amdgcn_mfma_f32_16x16x32_bf16(
                        af[mf], bf_[nf], acc[mf][nf], 0, 0, 0);
        }
        __syncthreads();   // reads done before restage
    }

    float bvv[4];
#pragma unroll
    for (int nf = 0; nf < 4; ++nf)
        bvv[nf] = bias[n0 + wn * 64 + nf * 16 + l15];

#pragma unroll
    for (int mf = 0; mf < 4; ++mf)
#pragma unroll
        for (int nf = 0; nf < 4; ++nf)
#pragma unroll
            for (int r = 0; r < 4; ++r) {
                // m89-verified C/D layout: col = lane&15, row = (lane>>4)*4+reg
                long row = m0 + wm * 64 + mf * 16 + g * 4 + r;
                long col = n0 + wn * 64 + nf * 16 + l15;
                float v = (acc[mf][nf][r] + bvv[nf]) * scale;
                stv(C + row * (long)N + col, v);
            }
}

__global__ __launch_bounds__(256) void proj_kernel(
    const unsigned short* __restrict__ xb, const unsigned short* __restrict__ wb,
    const float* __restrict__ bq, const float* __restrict__ bk,
    const float* __restrict__ bv, unsigned short* __restrict__ qkv) {
    int z = blockIdx.z;
    const float* bias = (z == 0) ? bq : (z == 1) ? bk : bv;
    float scale = (z == 0) ? QSCALE : 1.0f;
    gemm_core<unsigned short>(xb + (long)z * XE, wb + (long)z * WE, bias,
                              qkv + (long)z * XE, D_MODEL, D_MODEL, scale);
}

__global__ __launch_bounds__(256) void out_kernel(
    const unsigned short* __restrict__ ob, const unsigned short* __restrict__ wo,
    const float* __restrict__ bo, float* __restrict__ out) {
    gemm_core<float>(ob, wo, bo, out, D_MODEL, D_MODEL, 1.0f);
}

// ---------------------------------------------------------------------------
// Flash attention v4b (round-10, measured 63.4 us): block = 128 q rows, one
// (b,h); 8 waves x 16 rows. Swapped QK^T, defer-max THR=8, cvt_pk P-pack,
// l accumulated by ol = mfma(pf, ones, ol) in the PV loop.
// ---------------------------------------------------------------------------
#define KVB 4096   // elems per K/V buffer (64 rows x 64)

__global__ __launch_bounds__(512) void attn_kernel(
    const unsigned short* __restrict__ Qb, const unsigned short* __restrict__ Kb,
    const unsigned short* __restrict__ Vb, unsigned short* __restrict__ Ob) {
    __shared__ alignas(16) unsigned short Ks[2 * KVB];     // 16 KB
    __shared__ alignas(16) unsigned short Vt[2 * KVB];     // 16 KB  V^T [d][kv]
    __shared__ alignas(16) unsigned short Ps[8][16 * 64];  // 16 KB  per-wave P
    __shared__ alignas(16) float corrS[8][16];

    const int t = threadIdx.x, lane = t & 63, w = t >> 6;
    const int l15 = lane & 15, g = lane >> 4;
    const int bh = blockIdx.y;
    const long headoff = (long)(bh >> 4) * SEQ * D_MODEL + (long)(bh & 15) * DKH;
    const int q0w = blockIdx.x * 128 + w * 16;

    // Q rows -> B-frag registers (scale 0.125*log2e folded at projection)
    short8v qf[2];
#pragma unroll
    for (int ks = 0; ks < 2; ++ks)
        qf[ks] = *(const short8v*)(Qb + headoff +
            (long)(q0w + l15) * D_MODEL + ks * 32 + g * 8);

    // B-frag of all-ones (bf16 1.0 = 0x3F80) for the l-sum MFMA
    short8v onesv;
#pragma unroll
    for (int j = 0; j < 8; ++j) onesv[j] = (short)0x3F80;

    f32x4 o[4] = {};
    f32x4 ol = {};               // l accumulator via mfma(pf, ones, ol)
    float mrun = -3.0e38f;

    const int vd0  = (t & 31) * 2;    // V gather: this thread's d pair
    const int vkv0 = (t >> 5) * 4;    // and 4-kv group (t>>5 in 0..15)
    const int kr0 = t >> 3, ks0 = t & 7;   // K stage: one gload16 per thread

    unsigned int va[4];   // in-flight V gather regs (issue-early)

#define ISSUE_V(kt)                                                        \
    _Pragma("unroll")                                                      \
    for (int j = 0; j < 4; ++j)                                            \
        va[j] = *(const unsigned int*)(Vb + headoff +                      \
            (long)((kt) + vkv0 + j) * D_MODEL + vd0);

#define ISSUE_K(kt, off)                                                   \
    gload16(Kb + headoff + (long)((kt) + kr0) * D_MODEL +                  \
                ((ks0 ^ (kr0 & 7)) << 3), &Ks[(off) + t * 8]);

#define WRITE_V(off)                                                       \
    {                                                                      \
        short4v ra, rb;                                                    \
        _Pragma("unroll")                                                  \
        for (int j = 0; j < 4; ++j) {                                      \
            ra[j] = (short)(va[j] & 0xffffu);                              \
            rb[j] = (short)(va[j] >> 16);                                  \
        }                                                                  \
        *(short4v*)&Vt[(off) + swz_v(vd0,     vkv0)] = ra;                 \
        *(short4v*)&Vt[(off) + swz_v(vd0 + 1, vkv0)] = rb;                 \
    }

    // ---- prologue: drain Q loads, stage tile 0 into buffer 0 ----
    asm volatile("s_waitcnt vmcnt(0)" ::: "memory");
    ISSUE_V(0);
    ISSUE_K(0, 0);
    WRITE_V(0);              // compiler waits va (vmcnt(1)); K stays in flight
    int cur = 0;

    for (int it = 0; it < SEQ / 64; ++it) {
        const int nxt = cur ^ 1;
        const int ktn = (((it + 1) & (SEQ / 64 - 1))) * 64;  // wrapped prefetch
        ISSUE_V(ktn);
        ISSUE_K(ktn, nxt * KVB);
        // outstanding now: K(cur)=1 + V(nxt)=4 + K(nxt)=1 = 6; complete oldest
        asm volatile("s_waitcnt vmcnt(5)" ::: "memory");
        asm volatile("s_waitcnt lgkmcnt(0)" ::: "memory");
        __builtin_amdgcn_sched_barrier(0);
        __builtin_amdgcn_s_barrier();
        __builtin_amdgcn_sched_barrier(0);

        const int kO = cur * KVB;

        // ---- S^T = K * Q^T : lane holds S^T[kv = mf*16+g*4+r][q = l15] ----
        f32x4 st[4] = {};
        __builtin_amdgcn_s_setprio(1);
#pragma unroll
        for (int ks = 0; ks < 2; ++ks)
#pragma unroll
            for (int mf = 0; mf < 4; ++mf) {
                short8v kf = *(const short8v*)&Ks[kO + swz_u(mf * 16 + l15, ks * 32 + g * 8)];
                st[mf] = __builtin_amdgcn_mfma_f32_16x16x32_bf16(
                    kf, qf[ks], st[mf], 0, 0, 0);
            }
        __builtin_amdgcn_s_setprio(0);

        // ---- online softmax (exp2 domain), defer-max THR=8 ----
        float vmax = st[0][0];
#pragma unroll
        for (int mf = 0; mf < 4; ++mf)
#pragma unroll
            for (int r = 0; r < 4; ++r)
                vmax = fmaxf(vmax, st[mf][r]);
        vmax = fmaxf(vmax, __shfl_xor(vmax, 16));
        vmax = fmaxf(vmax, __shfl_xor(vmax, 32));

        const bool grow = __any(vmax > mrun + 8.0f);
        if (grow) {
            float mnew = fmaxf(mrun, vmax);
            float corr = fexp2(mrun - mnew);
            mrun = mnew;
            if (g == 0) corrS[w][l15] = corr;
        }

#pragma unroll
        for (int mf = 0; mf < 4; ++mf)
#pragma unroll
            for (int r = 0; r < 4; ++r)
                st[mf][r] = fexp2(st[mf][r] - mrun);

        // P: packed bf16 pairs (cvt_pk) -> b64 swizzled writes (wave-private)
        unsigned short* Pw = Ps[w];
#pragma unroll
        for (int mf = 0; mf < 4; ++mf) {
            uint2 pk;
            pk.x = cvt_pk_bf16(st[mf][0], st[mf][1]);
            pk.y = cvt_pk_bf16(st[mf][2], st[mf][3]);
            *(uint2*)&Pw[swz_u(l15, mf * 16 + g * 4)] = pk;
        }

        // rescale O and ol only when max grew (corr keyed by q = g*4 + r)
        if (grow) {
            float4 cv = *(const float4*)&corrS[w][g * 4];
#pragma unroll
            for (int nd = 0; nd < 4; ++nd)
#pragma unroll
                for (int r = 0; r < 4; ++r)
                    o[nd][r] *= cv[r];
#pragma unroll
            for (int r = 0; r < 4; ++r) ol[r] *= cv[r];
        }

        // ---- O += P * V ; ol += P * ones (row-sum of P) ----
        __builtin_amdgcn_s_setprio(1);
#pragma unroll
        for (int ks2 = 0; ks2 < 2; ++ks2) {
            short8v pf = *(const short8v*)&Pw[swz_u(l15, ks2 * 32 + g * 8)];
            ol = __builtin_amdgcn_mfma_f32_16x16x32_bf16(
                pf, onesv, ol, 0, 0, 0);
#pragma unroll
            for (int nd = 0; nd < 4; ++nd) {
                short8v vf = *(const short8v*)&Vt[kO + swz_v(nd * 16 + l15, ks2 * 32 + g * 8)];
                o[nd] = __builtin_amdgcn_mfma_f32_16x16x32_bf16(
                    pf, vf, o[nd], 0, 0, 0);
            }
        }
        __builtin_amdgcn_s_setprio(0);

        // ---- write next tile's V (regs arrived; compiler waits vmcnt) ----
        WRITE_V(nxt * KVB);
        cur = nxt;
    }

    // ---- epilogue: O /= l (l = ol, same D-layout as o) ----
#pragma unroll
    for (int r = 0; r < 4; ++r) {
        float inv = 1.f / (ol[r] + 1e-9f);
        long rowoff = headoff + (long)(q0w + g * 4 + r) * D_MODEL;
#pragma unroll
        for (int nd = 0; nd < 4; ++nd)
            Ob[rowoff + nd * 16 + l15] = f2bf(o[nd][r] * inv);
    }
#undef ISSUE_V
#undef ISSUE_K
#undef WRITE_V
}

// ---------------------------------------------------------------------------
// Launch
// ---------------------------------------------------------------------------
extern "C" void kernel_launch(void* const* d_in, const int* in_sizes, int n_in,
                              void* d_out, int out_size, void* d_ws, size_t ws_size,
                              hipStream_t stream) {
    // d_in order: 0 q, 1 k, 2 v, 3 Wq, 4 bq, 5 Wk, 6 bk, 7 Wv, 8 bv, 9 Wo, 10 bo
    unsigned short* ws  = (unsigned short*)d_ws;
    unsigned short* xb  = ws;                       // 3*XE  bf16 inputs q,k,v
    unsigned short* wb  = ws + 3L * XE;             // 4*WE  bf16 weights
    unsigned short* qkv = ws + 3L * XE + 4L * WE;   // 3*XE  Q(scaled), K, V
    unsigned short* ob  = qkv + 3L * XE;            // XE    attention output

    ConvArgs ca;
    ca.src[0] = (const float*)d_in[0]; ca.dst[0] = xb;           ca.n4[0] = (int)(XE / 4);
    ca.src[1] = (const float*)d_in[1]; ca.dst[1] = xb + XE;      ca.n4[1] = (int)(XE / 4);
    ca.src[2] = (const float*)d_in[2]; ca.dst[2] = xb + 2L * XE; ca.n4[2] = (int)(XE / 4);
    ca.src[3] = (const float*)d_in[3]; ca.dst[3] = wb;           ca.n4[3] = (int)(WE / 4);
    ca.src[4] = (const float*)d_in[5]; ca.dst[4] = wb + WE;      ca.n4[4] = (int)(WE / 4);
    ca.src[5] = (const float*)d_in[7]; ca.dst[5] = wb + 2L * WE; ca.n4[5] = (int)(WE / 4);
    ca.src[6] = (const float*)d_in[9]; ca.dst[6] = wb + 3L * WE; ca.n4[6] = (int)(WE / 4);

    hipLaunchKernelGGL(convert_kernel, dim3(512, 7), dim3(256), 0, stream, ca);

    hipLaunchKernelGGL(proj_kernel, dim3(8, 32, 3), dim3(256), 0, stream,
                       xb, wb, (const float*)d_in[4], (const float*)d_in[6],
                       (const float*)d_in[8], qkv);

    hipLaunchKernelGGL(attn_kernel, dim3(16, 32), dim3(512), 0, stream,
                       qkv, qkv + XE, qkv + 2L * XE, ob);

    hipLaunchKernelGGL(out_kernel, dim3(8, 32), dim3(256), 0, stream,
                       ob, wb + 3L * WE, (const float*)d_in[10], (float*)d_out);
}

// Round 17
// 135.983 us; speedup vs baseline: 1.0509x; 1.0509x over previous
//
#include <hip/hip_runtime.h>

// ---------------------------------------------------------------------------
// MultiHeadAttention forward, MI355X (gfx950).
// fp32->bf16 convert; Q/K/V projections (bf16 MFMA GEMM, BK=32, XCD-chunked
// block mapping for L2 A-panel reuse, Q scaled by 0.125*log2e); flash
// attention v4b (8 waves x 16q, swapped-QK^T, defer-max, cvt_pk P-pack,
// l via ones-MFMA, double-buffered K/V counted-vmcnt pipeline); out proj.
// ---------------------------------------------------------------------------

#define D_MODEL 1024
#define NHEADS  16
#define DKH     64
#define SEQ     2048
#define BATCH   2
#define MTOT    (BATCH * SEQ)            // 4096 rows
#define XE      ((long)MTOT * D_MODEL)   // 4194304 elems
#define WE      ((long)D_MODEL * D_MODEL)
#define QSCALE  0.18033688011112042f     // 0.125 * log2(e): softmax in exp2 domain

typedef __attribute__((ext_vector_type(8))) short short8v;   // 8 x bf16 (4 VGPR)
typedef __attribute__((ext_vector_type(4))) short short4v;   // 4 x bf16
typedef __attribute__((ext_vector_type(4))) float f32x4;     // MFMA C/D frag

typedef __attribute__((address_space(1))) void as1_void;
typedef __attribute__((address_space(3))) void as3_void;

__device__ __forceinline__ void gload16(const void* g, void* l) {
    __builtin_amdgcn_global_load_lds((const as1_void*)g, (as3_void*)l, 16, 0, 0);
}

__device__ __forceinline__ unsigned short f2bf(float x) {
    unsigned int u = __float_as_uint(x);
    u += 0x7FFFu + ((u >> 16) & 1u);     // RNE
    return (unsigned short)(u >> 16);
}

// native v_exp_f32: computes 2^x (avoid __exp2f: glibc name collision)
__device__ __forceinline__ float fexp2(float x) {
    return __builtin_amdgcn_exp2f(x);
}

// hardware packed f32x2 -> bf16x2 (one VALU op for two converts)
__device__ __forceinline__ unsigned int cvt_pk_bf16(float lo, float hi) {
    unsigned int r;
    asm("v_cvt_pk_bf16_f32 %0, %1, %2" : "=v"(r) : "v"(lo), "v"(hi));
    return r;
}

// XOR swizzle for [rows][64 bf16] LDS tiles (128B rows).
__device__ __forceinline__ int swz_u(int row, int col) {
    int byte = (col << 1) ^ ((row & 7) << 4);
    return (row << 6) + (byte >> 1);
}

// Vt swizzle: slot bits from (d&6)|((d>>3)&1): write pairs and reads stay 2-way.
__device__ __forceinline__ int swz_v(int d, int kv) {
    int slot = (d & 6) | ((d >> 3) & 1);
    int byte = (kv << 1) ^ (slot << 4);
    return (d << 6) + (byte >> 1);
}

// ---------------------------------------------------------------------------
// fp32 -> bf16 convert, 7 arrays in one launch (blockIdx.y selects array)
// ---------------------------------------------------------------------------
struct ConvArgs {
    const float*    src[7];
    unsigned short* dst[7];
    int             n4[7];
};

__global__ __launch_bounds__(256) void convert_kernel(ConvArgs a) {
    int z = blockIdx.y;
    const float4*   s = (const float4*)a.src[z];
    unsigned short* d = a.dst[z];
    int n = a.n4[z];
    for (int i = blockIdx.x * blockDim.x + threadIdx.x; i < n;
         i += gridDim.x * blockDim.x) {
        float4 v = s[i];
        ushort4 o;
        o.x = f2bf(v.x); o.y = f2bf(v.y); o.z = f2bf(v.z); o.w = f2bf(v.w);
        *(ushort4*)(d + 4L * i) = o;
    }
}

// ---------------------------------------------------------------------------
// GEMM: C[M,N] = A[M,K] * Bm[N,K]^T  (both K-major), + bias, * scale.
// 128x128 tile, BK=32, 4 waves (2x2), 16x16x32 bf16 MFMA, global_load_lds.
// m0/n0 passed in (callers apply XCD-chunked block mapping).
// ---------------------------------------------------------------------------
__device__ __forceinline__ void stv(float* p, float v)          { *p = v; }
__device__ __forceinline__ void stv(unsigned short* p, float v) { *p = f2bf(v); }

template <typename OutT>
__device__ __forceinline__ void gemm_core(const unsigned short* __restrict__ A,
                                          const unsigned short* __restrict__ Bm,
                                          const float* __restrict__ bias,
                                          OutT* __restrict__ C,
                                          int K, int N, float scale,
                                          long m0, long n0) {
    __shared__ unsigned short As[128 * 32];
    __shared__ unsigned short Bs[128 * 32];

    const int t    = threadIdx.x;
    const int lane = t & 63;
    const int w    = t >> 6;
    const int wm   = w >> 1, wn = w & 1;
    const int l15  = lane & 15, g = lane >> 4;

    f32x4 acc[4][4] = {};

    const int idx0 = t, idx1 = t + 256;
    const int r0 = idx0 >> 2, c0 = (idx0 & 3) * 8;
    const int r1 = idx1 >> 2, c1 = (idx1 & 3) * 8;
    const unsigned short* pa0 = A  + (m0 + r0) * K + c0;
    const unsigned short* pa1 = A  + (m0 + r1) * K + c1;
    const unsigned short* pb0 = Bm + (n0 + r0) * K + c0;
    const unsigned short* pb1 = Bm + (n0 + r1) * K + c1;

    for (int k0 = 0; k0 < K; k0 += 32) {
        gload16(pa0 + k0, &As[idx0 * 8]);
        gload16(pa1 + k0, &As[idx1 * 8]);
        gload16(pb0 + k0, &Bs[idx0 * 8]);
        gload16(pb1 + k0, &Bs[idx1 * 8]);
        __syncthreads();   // drains vmcnt -> LDS valid

        short8v af[4], bf_[4];
#pragma unroll
        for (int mf = 0; mf < 4; ++mf)
            af[mf] = *(const short8v*)&As[(wm * 64 + mf * 16 + l15) * 32 + g * 8];
#pragma unroll
        for (int nf = 0; nf < 4; ++nf)
            bf_[nf] = *(const short8v*)&Bs[(wn * 64 + nf * 16 + l15) * 32 + g * 8];
#pragma unroll
        for (int mf = 0; mf < 4; ++mf)
#pragma unroll
            for (int nf = 0; nf < 4; ++nf)
                acc[mf][nf] = __builtin_amdgcn_mfma_f32_16x16x32_bf16(
                    af[mf], bf_[nf], acc[mf][nf], 0, 0, 0);
        __syncthreads();   // reads done before restage
    }

    float bvv[4];
#pragma unroll
    for (int nf = 0; nf < 4; ++nf)
        bvv[nf] = bias[n0 + wn * 64 + nf * 16 + l15];

#pragma unroll
    for (int mf = 0; mf < 4; ++mf)
#pragma unroll
        for (int nf = 0; nf < 4; ++nf)
#pragma unroll
            for (int r = 0; r < 4; ++r) {
                // m89-verified C/D layout: col = lane&15, row = (lane>>4)*4+reg
                long row = m0 + wm * 64 + mf * 16 + g * 4 + r;
                long col = n0 + wn * 64 + nf * 16 + l15;
                float v = (acc[mf][nf][r] + bvv[nf]) * scale;
                stv(C + row * (long)N + col, v);
            }
}

// proj: 768 blocks, 1-D. XCD-chunked decode: XCD i owns M-rows 4i..4i+3
// across all (N-tile, z) -> A panels L2-resident per XCD (T1, bijective:
// 768 % 8 == 0).
__global__ __launch_bounds__(256) void proj_kernel(
    const unsigned short* __restrict__ xb, const unsigned short* __restrict__ wb,
    const float* __restrict__ bq, const float* __restrict__ bk,
    const float* __restrict__ bv, unsigned short* __restrict__ qkv) {
    const int bid = blockIdx.x;
    const int xcd = bid & 7;
    const int k   = bid >> 3;            // 0..95 = 4(y) x 8(x) x 3(z)
    const int ty  = (xcd << 2) | (k & 3);
    const int tx  = (k >> 2) & 7;
    const int z   = k >> 5;
    const float* bias = (z == 0) ? bq : (z == 1) ? bk : bv;
    float scale = (z == 0) ? QSCALE : 1.0f;
    gemm_core<unsigned short>(xb + (long)z * XE, wb + (long)z * WE, bias,
                              qkv + (long)z * XE, D_MODEL, D_MODEL, scale,
                              (long)ty * 128, (long)tx * 128);
}

// out: 256 blocks, 1-D, same chunked decode (256 % 8 == 0).
__global__ __launch_bounds__(256) void out_kernel(
    const unsigned short* __restrict__ ob, const unsigned short* __restrict__ wo,
    const float* __restrict__ bo, float* __restrict__ out) {
    const int bid = blockIdx.x;
    const int xcd = bid & 7;
    const int k   = bid >> 3;            // 0..31 = 4(y) x 8(x)
    const int ty  = (xcd << 2) | (k & 3);
    const int tx  = k >> 2;
    gemm_core<float>(ob, wo, bo, out, D_MODEL, D_MODEL, 1.0f,
                     (long)ty * 128, (long)tx * 128);
}

// ---------------------------------------------------------------------------
// Flash attention v4b (round-10, measured 63.4 us): block = 128 q rows, one
// (b,h); 8 waves x 16 rows. Swapped QK^T, defer-max THR=8, cvt_pk P-pack,
// l accumulated by ol = mfma(pf, ones, ol) in the PV loop.
// ---------------------------------------------------------------------------
#define KVB 4096   // elems per K/V buffer (64 rows x 64)

__global__ __launch_bounds__(512) void attn_kernel(
    const unsigned short* __restrict__ Qb, const unsigned short* __restrict__ Kb,
    const unsigned short* __restrict__ Vb, unsigned short* __restrict__ Ob) {
    __shared__ alignas(16) unsigned short Ks[2 * KVB];     // 16 KB
    __shared__ alignas(16) unsigned short Vt[2 * KVB];     // 16 KB  V^T [d][kv]
    __shared__ alignas(16) unsigned short Ps[8][16 * 64];  // 16 KB  per-wave P
    __shared__ alignas(16) float corrS[8][16];

    const int t = threadIdx.x, lane = t & 63, w = t >> 6;
    const int l15 = lane & 15, g = lane >> 4;
    const int bh = blockIdx.y;
    const long headoff = (long)(bh >> 4) * SEQ * D_MODEL + (long)(bh & 15) * DKH;
    const int q0w = blockIdx.x * 128 + w * 16;

    // Q rows -> B-frag registers (scale 0.125*log2e folded at projection)
    short8v qf[2];
#pragma unroll
    for (int ks = 0; ks < 2; ++ks)
        qf[ks] = *(const short8v*)(Qb + headoff +
            (long)(q0w + l15) * D_MODEL + ks * 32 + g * 8);

    // B-frag of all-ones (bf16 1.0 = 0x3F80) for the l-sum MFMA
    short8v onesv;
#pragma unroll
    for (int j = 0; j < 8; ++j) onesv[j] = (short)0x3F80;

    f32x4 o[4] = {};
    f32x4 ol = {};               // l accumulator via mfma(pf, ones, ol)
    float mrun = -3.0e38f;

    const int vd0  = (t & 31) * 2;    // V gather: this thread's d pair
    const int vkv0 = (t >> 5) * 4;    // and 4-kv group (t>>5 in 0..15)
    const int kr0 = t >> 3, ks0 = t & 7;   // K stage: one gload16 per thread

    unsigned int va[4];   // in-flight V gather regs (issue-early)

#define ISSUE_V(kt)                                                        \
    _Pragma("unroll")                                                      \
    for (int j = 0; j < 4; ++j)                                            \
        va[j] = *(const unsigned int*)(Vb + headoff +                      \
            (long)((kt) + vkv0 + j) * D_MODEL + vd0);

#define ISSUE_K(kt, off)                                                   \
    gload16(Kb + headoff + (long)((kt) + kr0) * D_MODEL +                  \
                ((ks0 ^ (kr0 & 7)) << 3), &Ks[(off) + t * 8]);

#define WRITE_V(off)                                                       \
    {                                                                      \
        short4v ra, rb;                                                    \
        _Pragma("unroll")                                                  \
        for (int j = 0; j < 4; ++j) {                                      \
            ra[j] = (short)(va[j] & 0xffffu);                              \
            rb[j] = (short)(va[j] >> 16);                                  \
        }                                                                  \
        *(short4v*)&Vt[(off) + swz_v(vd0,     vkv0)] = ra;                 \
        *(short4v*)&Vt[(off) + swz_v(vd0 + 1, vkv0)] = rb;                 \
    }

    // ---- prologue: drain Q loads, stage tile 0 into buffer 0 ----
    asm volatile("s_waitcnt vmcnt(0)" ::: "memory");
    ISSUE_V(0);
    ISSUE_K(0, 0);
    WRITE_V(0);              // compiler waits va (vmcnt(1)); K stays in flight
    int cur = 0;

    for (int it = 0; it < SEQ / 64; ++it) {
        const int nxt = cur ^ 1;
        const int ktn = (((it + 1) & (SEQ / 64 - 1))) * 64;  // wrapped prefetch
        ISSUE_V(ktn);
        ISSUE_K(ktn, nxt * KVB);
        // outstanding now: K(cur)=1 + V(nxt)=4 + K(nxt)=1 = 6; complete oldest
        asm volatile("s_waitcnt vmcnt(5)" ::: "memory");
        asm volatile("s_waitcnt lgkmcnt(0)" ::: "memory");
        __builtin_amdgcn_sched_barrier(0);
        __builtin_amdgcn_s_barrier();
        __builtin_amdgcn_sched_barrier(0);

        const int kO = cur * KVB;

        // ---- S^T = K * Q^T : lane holds S^T[kv = mf*16+g*4+r][q = l15] ----
        f32x4 st[4] = {};
        __builtin_amdgcn_s_setprio(1);
#pragma unroll
        for (int ks = 0; ks < 2; ++ks)
#pragma unroll
            for (int mf = 0; mf < 4; ++mf) {
                short8v kf = *(const short8v*)&Ks[kO + swz_u(mf * 16 + l15, ks * 32 + g * 8)];
                st[mf] = __builtin_amdgcn_mfma_f32_16x16x32_bf16(
                    kf, qf[ks], st[mf], 0, 0, 0);
            }
        __builtin_amdgcn_s_setprio(0);

        // ---- online softmax (exp2 domain), defer-max THR=8 ----
        float vmax = st[0][0];
#pragma unroll
        for (int mf = 0; mf < 4; ++mf)
#pragma unroll
            for (int r = 0; r < 4; ++r)
                vmax = fmaxf(vmax, st[mf][r]);
        vmax = fmaxf(vmax, __shfl_xor(vmax, 16));
        vmax = fmaxf(vmax, __shfl_xor(vmax, 32));

        const bool grow = __any(vmax > mrun + 8.0f);
        if (grow) {
            float mnew = fmaxf(mrun, vmax);
            float corr = fexp2(mrun - mnew);
            mrun = mnew;
            if (g == 0) corrS[w][l15] = corr;
        }

#pragma unroll
        for (int mf = 0; mf < 4; ++mf)
#pragma unroll
            for (int r = 0; r < 4; ++r)
                st[mf][r] = fexp2(st[mf][r] - mrun);

        // P: packed bf16 pairs (cvt_pk) -> b64 swizzled writes (wave-private)
        unsigned short* Pw = Ps[w];
#pragma unroll
        for (int mf = 0; mf < 4; ++mf) {
            uint2 pk;
            pk.x = cvt_pk_bf16(st[mf][0], st[mf][1]);
            pk.y = cvt_pk_bf16(st[mf][2], st[mf][3]);
            *(uint2*)&Pw[swz_u(l15, mf * 16 + g * 4)] = pk;
        }

        // rescale O and ol only when max grew (corr keyed by q = g*4 + r)
        if (grow) {
            float4 cv = *(const float4*)&corrS[w][g * 4];
#pragma unroll
            for (int nd = 0; nd < 4; ++nd)
#pragma unroll
                for (int r = 0; r < 4; ++r)
                    o[nd][r] *= cv[r];
#pragma unroll
            for (int r = 0; r < 4; ++r) ol[r] *= cv[r];
        }

        // ---- O += P * V ; ol += P * ones (row-sum of P) ----
        __builtin_amdgcn_s_setprio(1);
#pragma unroll
        for (int ks2 = 0; ks2 < 2; ++ks2) {
            short8v pf = *(const short8v*)&Pw[swz_u(l15, ks2 * 32 + g * 8)];
            ol = __builtin_amdgcn_mfma_f32_16x16x32_bf16(
                pf, onesv, ol, 0, 0, 0);
#pragma unroll
            for (int nd = 0; nd < 4; ++nd) {
                short8v vf = *(const short8v*)&Vt[kO + swz_v(nd * 16 + l15, ks2 * 32 + g * 8)];
                o[nd] = __builtin_amdgcn_mfma_f32_16x16x32_bf16(
                    pf, vf, o[nd], 0, 0, 0);
            }
        }
        __builtin_amdgcn_s_setprio(0);

        // ---- write next tile's V (regs arrived; compiler waits vmcnt) ----
        WRITE_V(nxt * KVB);
        cur = nxt;
    }

    // ---- epilogue: O /= l (l = ol, same D-layout as o) ----
#pragma unroll
    for (int r = 0; r < 4; ++r) {
        float inv = 1.f / (ol[r] + 1e-9f);
        long rowoff = headoff + (long)(q0w + g * 4 + r) * D_MODEL;
#pragma unroll
        for (int nd = 0; nd < 4; ++nd)
            Ob[rowoff + nd * 16 + l15] = f2bf(o[nd][r] * inv);
    }
#undef ISSUE_V
#undef ISSUE_K
#undef WRITE_V
}

// ---------------------------------------------------------------------------
// Launch
// ---------------------------------------------------------------------------
extern "C" void kernel_launch(void* const* d_in, const int* in_sizes, int n_in,
                              void* d_out, int out_size, void* d_ws, size_t ws_size,
                              hipStream_t stream) {
    // d_in order: 0 q, 1 k, 2 v, 3 Wq, 4 bq, 5 Wk, 6 bk, 7 Wv, 8 bv, 9 Wo, 10 bo
    unsigned short* ws  = (unsigned short*)d_ws;
    unsigned short* xb  = ws;                       // 3*XE  bf16 inputs q,k,v
    unsigned short* wb  = ws + 3L * XE;             // 4*WE  bf16 weights
    unsigned short* qkv = ws + 3L * XE + 4L * WE;   // 3*XE  Q(scaled), K, V
    unsigned short* ob  = qkv + 3L * XE;            // XE    attention output

    ConvArgs ca;
    ca.src[0] = (const float*)d_in[0]; ca.dst[0] = xb;           ca.n4[0] = (int)(XE / 4);
    ca.src[1] = (const float*)d_in[1]; ca.dst[1] = xb + XE;      ca.n4[1] = (int)(XE / 4);
    ca.src[2] = (const float*)d_in[2]; ca.dst[2] = xb + 2L * XE; ca.n4[2] = (int)(XE / 4);
    ca.src[3] = (const float*)d_in[3]; ca.dst[3] = wb;           ca.n4[3] = (int)(WE / 4);
    ca.src[4] = (const float*)d_in[5]; ca.dst[4] = wb + WE;      ca.n4[4] = (int)(WE / 4);
    ca.src[5] = (const float*)d_in[7]; ca.dst[5] = wb + 2L * WE; ca.n4[5] = (int)(WE / 4);
    ca.src[6] = (const float*)d_in[9]; ca.dst[6] = wb + 3L * WE; ca.n4[6] = (int)(WE / 4);

    hipLaunchKernelGGL(convert_kernel, dim3(512, 7), dim3(256), 0, stream, ca);

    hipLaunchKernelGGL(proj_kernel, dim3(768), dim3(256), 0, stream,
                       xb, wb, (const float*)d_in[4], (const float*)d_in[6],
                       (const float*)d_in[8], qkv);

    hipLaunchKernelGGL(attn_kernel, dim3(16, 32), dim3(512), 0, stream,
                       qkv, qkv + XE, qkv + 2L * XE, ob);

    hipLaunchKernelGGL(out_kernel, dim3(256), dim3(256), 0, stream,
                       ob, wb + 3L * WE, (const float*)d_in[10], (float*)d_out);
}